// Round 1
// baseline (16784.418 us; speedup 1.0000x reference)
//
#include <hip/hip_runtime.h>
#include <hip/hip_fp16.h>
#include <cstdint>
#include <cstddef>

// LSTM 3-layer, H=2048, B=16, T=128, I=128, O=1 (fp32 in/out).
// Strategy:
//  - All matmuls in fp16 MFMA (16x16x32_f16, fp32 accum). Gate math / c-state fp32.
//  - x_proj per layer: tiled NT-GEMM (128x128 tile, BK=64, global_load_lds 16B).
//  - Recurrent scan: persistent kernel, 256 blocks (1/CU), W_hh slice (32 rows)
//    fp16 in LDS (128KB, XOR-swizzled), double-buffered h + flag barrier.
// ws usage ~118.1 MB.

typedef __attribute__((ext_vector_type(8))) _Float16 fp16x8;
typedef __attribute__((ext_vector_type(4))) float    f32x4;

#define HDIM  2048
#define GATES 8192
#define BATCH 16
#define TSEQ  128
#define NTOK  2048                 // BATCH*TSEQ
#define SCAN_LDS_BYTES (131072 + 8192)

__device__ __forceinline__ float sigmoidf_(float x) { return 1.f / (1.f + __expf(-x)); }
__device__ __forceinline__ float tanhf_(float x) {
    float e2 = __expf(2.f * x);
    return 1.f - 2.f / (e2 + 1.f);   // handles +-inf correctly -> +-1
}

// ---------------- fp32 -> fp16 conversion (vectorized, 8 elems/thread) -------
__global__ __launch_bounds__(256) void cvt_f32_f16_kernel(const float* __restrict__ in,
                                                          _Float16* __restrict__ out, int n8) {
    int i = blockIdx.x * 256 + threadIdx.x;
    if (i >= n8) return;
    const float4* p = (const float4*)in + (size_t)i * 2;
    float4 a = p[0], b = p[1];
    fp16x8 v;
    v[0] = (_Float16)a.x; v[1] = (_Float16)a.y; v[2] = (_Float16)a.z; v[3] = (_Float16)a.w;
    v[4] = (_Float16)b.x; v[5] = (_Float16)b.y; v[6] = (_Float16)b.z; v[7] = (_Float16)b.w;
    ((fp16x8*)out)[i] = v;
}

// ---------------- x_proj GEMM: xp[t][n][b] = A[m][:]·W[n][:] + bih[n]+bhh[n] --
// A: [NTOK][K] fp16 (m = b*128 + t), W: [GATES][K] fp16. 128x128 tile, BK=64.
__global__ __launch_bounds__(256) void xproj_gemm_kernel(
        const _Float16* __restrict__ A, const _Float16* __restrict__ W,
        const float* __restrict__ bih, const float* __restrict__ bhh,
        float* __restrict__ xp, int K) {
    __shared__ _Float16 As[128 * 64];
    __shared__ _Float16 Bs[128 * 64];
    const int tid  = threadIdx.x;
    const int lane = tid & 63;
    const int wave = tid >> 6;
    const int n0 = blockIdx.x * 128;
    const int m0 = blockIdx.y * 128;
    const int srow = tid >> 3;          // staging row within 32-row chunk
    const int scol = (tid & 7) * 8;     // staging col (halves)
    const int wr = (wave >> 1) * 64;    // wave sub-tile
    const int wc = (wave & 1) * 64;
    const int lr = lane & 15;
    const int lk = (lane >> 4) * 8;

    f32x4 acc[4][4] = {};

    const int nk = K >> 6;
    for (int kt = 0; kt < nk; ++kt) {
        if (kt) __syncthreads();
        const int k0 = kt * 64;
#pragma unroll
        for (int cc = 0; cc < 4; ++cc) {
            const int row = cc * 32 + srow;
            const _Float16* ga = A + (size_t)(m0 + row) * K + k0 + scol;
            const _Float16* gb = W + (size_t)(n0 + row) * K + k0 + scol;
            __builtin_amdgcn_global_load_lds(
                (const __attribute__((address_space(1))) void*)ga,
                (__attribute__((address_space(3))) void*)(As + cc * 2048 + wave * 512), 16, 0, 0);
            __builtin_amdgcn_global_load_lds(
                (const __attribute__((address_space(1))) void*)gb,
                (__attribute__((address_space(3))) void*)(Bs + cc * 2048 + wave * 512), 16, 0, 0);
        }
        __syncthreads();   // drains vmcnt before compute
#pragma unroll
        for (int s = 0; s < 2; ++s) {
            fp16x8 af[4], bf[4];
#pragma unroll
            for (int mi = 0; mi < 4; ++mi)
                af[mi] = *(const fp16x8*)(As + (wr + mi * 16 + lr) * 64 + s * 32 + lk);
#pragma unroll
            for (int ni = 0; ni < 4; ++ni)
                bf[ni] = *(const fp16x8*)(Bs + (wc + ni * 16 + lr) * 64 + s * 32 + lk);
#pragma unroll
            for (int mi = 0; mi < 4; ++mi)
#pragma unroll
                for (int ni = 0; ni < 4; ++ni)
                    acc[mi][ni] = __builtin_amdgcn_mfma_f32_16x16x32_f16(
                        af[mi], bf[ni], acc[mi][ni], 0, 0, 0);
        }
    }
    // epilogue: scatter to xp[t][n][b] (scan-friendly layout), add biases
    const int rb = (lane >> 4) * 4;
#pragma unroll
    for (int ni = 0; ni < 4; ++ni) {
        const int n = n0 + wc + ni * 16 + lr;
        const float bias = bih[n] + bhh[n];
#pragma unroll
        for (int mi = 0; mi < 4; ++mi) {
#pragma unroll
            for (int r = 0; r < 4; ++r) {
                const int m = m0 + wr + mi * 16 + rb + r;
                const int b = m >> 7, t = m & 127;
                xp[((size_t)t * GATES + n) * BATCH + b] = acc[mi][ni][r] + bias;
            }
        }
    }
}

// ---------------- persistent LSTM scan --------------------------------------
// 256 blocks x 256 threads; block owns 8 hidden units (32 W_hh rows) in LDS fp16.
// Per step: 4 waves split K (512 each), MFMA partials -> LDS reduce -> 128
// update threads do gate math + write h (fp16) -> flag barrier (agent scope).
__global__ __launch_bounds__(256) void lstm_scan_kernel(
        const float* __restrict__ Whh,   // [GATES][HDIM] fp32
        const float* __restrict__ xp,    // [TSEQ][GATES][BATCH] fp32
        _Float16* __restrict__ hseq,     // [BATCH][TSEQ][HDIM] out
        _Float16* __restrict__ hbuf,     // [2][BATCH][HDIM] (zeroed before launch)
        int* __restrict__ flags) {       // [256] (zeroed before launch)
    extern __shared__ char smem[];                    // [32][2048] fp16 W (swizzled)
    float* red = (float*)(smem + 131072);             // [4][2][16][16] partials

    const int tid  = threadIdx.x;
    const int lane = tid & 63;
    const int wave = tid >> 6;
    const int blk  = blockIdx.x;
    const int h0   = blk * 8;

    {   // stage W_hh rows {q*2048 + h0 + j} -> LDS row r=q*8+j, fp16, XOR-swizzled
        const int r = tid & 31;
        const int q = r >> 3, j = r & 7;
        const float* wrow = Whh + (size_t)(q * HDIM + h0 + j) * HDIM;
        const int c0 = (tid >> 5) * 256;
        for (int k = c0; k < c0 + 256; k += 8) {
            float4 f0 = *(const float4*)(wrow + k);
            float4 f1 = *(const float4*)(wrow + k + 4);
            fp16x8 v;
            v[0] = (_Float16)f0.x; v[1] = (_Float16)f0.y; v[2] = (_Float16)f0.z; v[3] = (_Float16)f0.w;
            v[4] = (_Float16)f1.x; v[5] = (_Float16)f1.y; v[6] = (_Float16)f1.z; v[7] = (_Float16)f1.w;
            uint32_t byte = (uint32_t)(r * 4096 + k * 2) ^ (uint32_t)((r & 7) << 4);
            *(fp16x8*)(smem + byte) = v;
        }
    }
    __syncthreads();

    float c_state = 0.f;                     // owned by tid<128 (b=tid&15, hid=tid>>4)
    const int ln15 = lane & 15;
    const int kl   = (lane >> 4) * 8;
    const uint32_t sw   = (uint32_t)((ln15 & 7) << 4);
    const uint32_t row0 = (uint32_t)ln15 * 4096u;
    const uint32_t row1 = row0 + 16u * 4096u;
    const int kbase = wave * 512;
    const int ub = tid & 15;
    const int uh = tid >> 4;

    for (int t = 0; t < 128; ++t) {
        // wait: all blocks published h_{t-1}
        while (__hip_atomic_load(flags + tid, __ATOMIC_RELAXED, __HIP_MEMORY_SCOPE_AGENT) < t)
            __builtin_amdgcn_s_sleep(1);
        __threadfence();                     // acquire: invalidate L1/L2 before h reads
        __syncthreads();

        const _Float16* hprev = hbuf + ((size_t)((t + 1) & 1)) * (BATCH * HDIM)
                              + (size_t)ln15 * HDIM;
        f32x4 acc0 = {0.f, 0.f, 0.f, 0.f};
        f32x4 acc1 = {0.f, 0.f, 0.f, 0.f};
#pragma unroll 4
        for (int s = 0; s < 16; ++s) {
            const int k = kbase + s * 32 + kl;
            fp16x8 af = *(const fp16x8*)(hprev + k);                       // A: h[b][k..k+7]
            const uint32_t kb = (uint32_t)(k * 2);
            fp16x8 b0 = *(const fp16x8*)(smem + ((row0 + kb) ^ sw));       // B tile0 (i,f)
            fp16x8 b1 = *(const fp16x8*)(smem + ((row1 + kb) ^ sw));       // B tile1 (g,o)
            acc0 = __builtin_amdgcn_mfma_f32_16x16x32_f16(af, b0, acc0, 0, 0, 0);
            acc1 = __builtin_amdgcn_mfma_f32_16x16x32_f16(af, b1, acc1, 0, 0, 0);
        }
        {   // write per-wave partials: red[w][tile][col][batch]
            float* r0 = red + (((wave * 2 + 0) * 16 + ln15) * 16) + (lane >> 4) * 4;
            float* r1 = red + (((wave * 2 + 1) * 16 + ln15) * 16) + (lane >> 4) * 4;
#pragma unroll
            for (int i = 0; i < 4; ++i) { r0[i] = acc0[i]; r1[i] = acc1[i]; }
        }
        __syncthreads();

        if (tid < 128) {
            float ip = 0.f, fp_ = 0.f, gp = 0.f, op = 0.f;
#pragma unroll
            for (int w = 0; w < 4; ++w) {
                ip  += red[((w * 2 + 0) * 16 + uh    ) * 16 + ub];
                fp_ += red[((w * 2 + 0) * 16 + uh + 8) * 16 + ub];
                gp  += red[((w * 2 + 1) * 16 + uh    ) * 16 + ub];
                op  += red[((w * 2 + 1) * 16 + uh + 8) * 16 + ub];
            }
            const float* xpt = xp + (size_t)t * GATES * BATCH;
            const int nb = h0 + uh;
            ip  += xpt[((size_t)(0 * HDIM + nb)) * BATCH + ub];
            fp_ += xpt[((size_t)(1 * HDIM + nb)) * BATCH + ub];
            gp  += xpt[((size_t)(2 * HDIM + nb)) * BATCH + ub];
            op  += xpt[((size_t)(3 * HDIM + nb)) * BATCH + ub];
            float ig = sigmoidf_(ip), fg = sigmoidf_(fp_), og = sigmoidf_(op);
            float gg = tanhf_(gp);
            c_state = fg * c_state + ig * gg;
            float hv = og * tanhf_(c_state);
            _Float16 hh = (_Float16)hv;
            hbuf[((size_t)(t & 1)) * (BATCH * HDIM) + (size_t)ub * HDIM + nb] = hh;
            hseq[((size_t)ub * TSEQ + t) * HDIM + nb] = hh;
        }
        __syncthreads();                     // all h writes drained (vmcnt 0 at barrier)
        __threadfence();                     // release: flush to agent coherence point
        if (tid == 0)
            __hip_atomic_store(flags + blk, t + 1, __ATOMIC_RELAXED, __HIP_MEMORY_SCOPE_AGENT);
    }
}

// ---------------- output projection: out[tok] = h[tok][:]·Wout + bout --------
__global__ __launch_bounds__(256) void outproj_kernel(
        const _Float16* __restrict__ hseq, const float* __restrict__ Wout,
        const float* __restrict__ bout, float* __restrict__ out) {
    const int lane = threadIdx.x & 63;
    const int wave = threadIdx.x >> 6;
    const int tok = blockIdx.x * 4 + wave;
    const _Float16* h = hseq + (size_t)tok * HDIM;
    float acc = 0.f;
#pragma unroll
    for (int c = 0; c < 4; ++c) {
        const int k = c * 512 + lane * 8;
        fp16x8 hv = *(const fp16x8*)(h + k);
        const float* w = Wout + k;
#pragma unroll
        for (int i = 0; i < 8; ++i) acc += (float)hv[i] * w[i];
    }
#pragma unroll
    for (int off = 32; off > 0; off >>= 1) acc += __shfl_down(acc, off, 64);
    if (lane == 0) out[tok] = acc + bout[0];
}

// ---------------- launch -----------------------------------------------------
extern "C" void kernel_launch(void* const* d_in, const int* in_sizes, int n_in,
                              void* d_out, int out_size, void* d_ws, size_t ws_size,
                              hipStream_t stream) {
    (void)in_sizes; (void)n_in; (void)out_size; (void)ws_size;
    const float* x       = (const float*)d_in[0];
    const float* Wih[3]  = {(const float*)d_in[1], (const float*)d_in[5], (const float*)d_in[9]};
    const float* Whh[3]  = {(const float*)d_in[2], (const float*)d_in[6], (const float*)d_in[10]};
    const float* bih[3]  = {(const float*)d_in[3], (const float*)d_in[7], (const float*)d_in[11]};
    const float* bhh[3]  = {(const float*)d_in[4], (const float*)d_in[8], (const float*)d_in[12]};
    const float* Wout    = (const float*)d_in[13];
    const float* bout    = (const float*)d_in[14];
    float* out = (float*)d_out;

    char* ws = (char*)d_ws;
    size_t off = 0;
    auto carve = [&](size_t bytes) {
        char* p = ws + off;
        off += (bytes + 255) & ~(size_t)255;
        return p;
    };
    _Float16* wih16 = (_Float16*)carve((size_t)GATES * 2048 * 2);          // 33.5 MB
    float*    xp    = (float*)   carve((size_t)TSEQ * GATES * BATCH * 4);  // 67 MB
    _Float16* hseqA = (_Float16*)carve((size_t)NTOK * HDIM * 2);           // 8.4 MB
    _Float16* hseqB = (_Float16*)carve((size_t)NTOK * HDIM * 2);           // 8.4 MB
    _Float16* xh    = (_Float16*)carve((size_t)NTOK * 128 * 2);            // 0.5 MB
    _Float16* hbuf  = (_Float16*)carve((size_t)2 * BATCH * HDIM * 2);      // 128 KB
    int*      flags = (int*)     carve(256 * 4);

    hipFuncSetAttribute((const void*)lstm_scan_kernel,
                        hipFuncAttributeMaxDynamicSharedMemorySize, SCAN_LDS_BYTES);

    // x -> fp16
    {
        int n8 = NTOK * 128 / 8;
        cvt_f32_f16_kernel<<<(n8 + 255) / 256, 256, 0, stream>>>(x, xh, n8);
    }

    const _Float16* Ain[3] = {xh, hseqA, hseqB};
    _Float16*       Hout[3] = {hseqA, hseqB, hseqA};
    const int       Kl[3]   = {128, 2048, 2048};

    for (int l = 0; l < 3; ++l) {
        int n8 = GATES * Kl[l] / 8;
        cvt_f32_f16_kernel<<<(n8 + 255) / 256, 256, 0, stream>>>(Wih[l], wih16, n8);
        dim3 ggrid(GATES / 128, NTOK / 128);
        xproj_gemm_kernel<<<ggrid, 256, 0, stream>>>(Ain[l], wih16, bih[l], bhh[l], xp, Kl[l]);
        hipMemsetAsync(flags, 0, 256 * 4, stream);
        hipMemsetAsync(hbuf, 0, (size_t)2 * BATCH * HDIM * 2, stream);
        lstm_scan_kernel<<<256, 256, SCAN_LDS_BYTES, stream>>>(Whh[l], xp, Hout[l], hbuf, flags);
    }
    outproj_kernel<<<NTOK / 4, 256, 0, stream>>>(hseqA, Wout, bout, out);
}

// Round 2
// 3943.570 us; speedup vs baseline: 4.2561x; 4.2561x over previous
//
#include <hip/hip_runtime.h>
#include <hip/hip_fp16.h>
#include <cstdint>
#include <cstddef>

// LSTM 3-layer, H=2048, B=16, T=128, I=128, O=1 (fp32 in/out).
//  - All matmuls fp16 MFMA (16x16x32_f16, fp32 accum). Gate math / c-state fp32.
//  - x_proj per layer: tiled NT-GEMM (128x128 tile, BK=64, global_load_lds 16B).
//  - Recurrent scan: persistent kernel, 256 blocks (1/CU), W_hh slice (32 rows)
//    fp16 in LDS (128KB, XOR-swizzled), double-buffered h + flag barrier.
//  - R2: NO __threadfence (buffer_wbl2/inv was 42us/step). All cross-block h
//    traffic via relaxed agent-scope atomics (L3-bypass point-to-point),
//    ordering via per-wave vmcnt(0) + s_barrier before flag publish.

typedef __attribute__((ext_vector_type(8))) _Float16 fp16x8;
typedef __attribute__((ext_vector_type(4))) _Float16 fp16x4;
typedef __attribute__((ext_vector_type(4))) float    f32x4;

#define HDIM  2048
#define GATES 8192
#define BATCH 16
#define TSEQ  128
#define NTOK  2048                 // BATCH*TSEQ
#define RED_STRIDE 17
#define SCAN_LDS_BYTES (131072 + 8 * 16 * RED_STRIDE * 4)

union U8  { unsigned long long u; fp16x4 h4; };
union HU  { _Float16 f; unsigned short u; };

__device__ __forceinline__ float sigmoidf_(float x) { return 1.f / (1.f + __expf(-x)); }
__device__ __forceinline__ float tanhf_(float x) {
    float e2 = __expf(2.f * x);
    return 1.f - 2.f / (e2 + 1.f);   // handles +-inf correctly -> +-1
}

// ---------------- fp32 -> fp16 conversion (vectorized, 8 elems/thread) -------
__global__ __launch_bounds__(256) void cvt_f32_f16_kernel(const float* __restrict__ in,
                                                          _Float16* __restrict__ out, int n8) {
    int i = blockIdx.x * 256 + threadIdx.x;
    if (i >= n8) return;
    const float4* p = (const float4*)in + (size_t)i * 2;
    float4 a = p[0], b = p[1];
    fp16x8 v;
    v[0] = (_Float16)a.x; v[1] = (_Float16)a.y; v[2] = (_Float16)a.z; v[3] = (_Float16)a.w;
    v[4] = (_Float16)b.x; v[5] = (_Float16)b.y; v[6] = (_Float16)b.z; v[7] = (_Float16)b.w;
    ((fp16x8*)out)[i] = v;
}

// ---------------- x_proj GEMM: xp[t][n][b] = A[m][:]·W[n][:] + bih[n]+bhh[n] --
// A: [NTOK][K] fp16 (m = b*128 + t), W: [GATES][K] fp16. 128x128 tile, BK=64.
__global__ __launch_bounds__(256) void xproj_gemm_kernel(
        const _Float16* __restrict__ A, const _Float16* __restrict__ W,
        const float* __restrict__ bih, const float* __restrict__ bhh,
        float* __restrict__ xp, int K) {
    __shared__ _Float16 As[128 * 64];
    __shared__ _Float16 Bs[128 * 64];
    const int tid  = threadIdx.x;
    const int lane = tid & 63;
    const int wave = tid >> 6;
    const int n0 = blockIdx.x * 128;
    const int m0 = blockIdx.y * 128;
    const int srow = tid >> 3;          // staging row within 32-row chunk
    const int scol = (tid & 7) * 8;     // staging col (halves)
    const int wr = (wave >> 1) * 64;    // wave sub-tile
    const int wc = (wave & 1) * 64;
    const int lr = lane & 15;
    const int lk = (lane >> 4) * 8;

    f32x4 acc[4][4] = {};

    const int nk = K >> 6;
    for (int kt = 0; kt < nk; ++kt) {
        if (kt) __syncthreads();
        const int k0 = kt * 64;
#pragma unroll
        for (int cc = 0; cc < 4; ++cc) {
            const int row = cc * 32 + srow;
            const _Float16* ga = A + (size_t)(m0 + row) * K + k0 + scol;
            const _Float16* gb = W + (size_t)(n0 + row) * K + k0 + scol;
            __builtin_amdgcn_global_load_lds(
                (const __attribute__((address_space(1))) void*)ga,
                (__attribute__((address_space(3))) void*)(As + cc * 2048 + wave * 512), 16, 0, 0);
            __builtin_amdgcn_global_load_lds(
                (const __attribute__((address_space(1))) void*)gb,
                (__attribute__((address_space(3))) void*)(Bs + cc * 2048 + wave * 512), 16, 0, 0);
        }
        __syncthreads();   // drains vmcnt before compute
#pragma unroll
        for (int s = 0; s < 2; ++s) {
            fp16x8 af[4], bf[4];
#pragma unroll
            for (int mi = 0; mi < 4; ++mi)
                af[mi] = *(const fp16x8*)(As + (wr + mi * 16 + lr) * 64 + s * 32 + lk);
#pragma unroll
            for (int ni = 0; ni < 4; ++ni)
                bf[ni] = *(const fp16x8*)(Bs + (wc + ni * 16 + lr) * 64 + s * 32 + lk);
#pragma unroll
            for (int mi = 0; mi < 4; ++mi)
#pragma unroll
                for (int ni = 0; ni < 4; ++ni)
                    acc[mi][ni] = __builtin_amdgcn_mfma_f32_16x16x32_f16(
                        af[mi], bf[ni], acc[mi][ni], 0, 0, 0);
        }
    }
    // epilogue: scatter to xp[t][n][b] (scan-friendly layout), add biases
    const int rb = (lane >> 4) * 4;
#pragma unroll
    for (int ni = 0; ni < 4; ++ni) {
        const int n = n0 + wc + ni * 16 + lr;
        const float bias = bih[n] + bhh[n];
#pragma unroll
        for (int mi = 0; mi < 4; ++mi) {
#pragma unroll
            for (int r = 0; r < 4; ++r) {
                const int m = m0 + wr + mi * 16 + rb + r;
                const int b = m >> 7, t = m & 127;
                xp[((size_t)t * GATES + n) * BATCH + b] = acc[mi][ni][r] + bias;
            }
        }
    }
}

// ---------------- persistent LSTM scan --------------------------------------
// 256 blocks x 256 threads; block owns 8 hidden units (32 W_hh rows) in LDS fp16.
// Per step: 4 waves split K (512 each), MFMA partials -> LDS reduce -> 128
// update threads do gate math + publish h via relaxed agent atomics (no fences).
__global__ __launch_bounds__(256) void lstm_scan_kernel(
        const float* __restrict__ Whh,   // [GATES][HDIM] fp32
        const float* __restrict__ xp,    // [TSEQ][GATES][BATCH] fp32
        _Float16* __restrict__ hseq,     // [BATCH][TSEQ][HDIM] out
        _Float16* __restrict__ hbuf,     // [2][BATCH][HDIM] (zeroed before launch)
        int* __restrict__ flags) {       // [256] (zeroed before launch)
    extern __shared__ char smem[];                    // [32][2048] fp16 W (swizzled)
    float* red = (float*)(smem + 131072);             // [8 tiles][16 n][RED_STRIDE]

    const int tid  = threadIdx.x;
    const int lane = tid & 63;
    const int wave = tid >> 6;
    const int blk  = blockIdx.x;
    const int h0   = blk * 8;

    {   // stage W_hh rows {q*2048 + h0 + j} -> LDS row r=q*8+j, fp16, XOR-swizzled
        const int r = tid & 31;
        const int q = r >> 3, j = r & 7;
        const float* wrow = Whh + (size_t)(q * HDIM + h0 + j) * HDIM;
        const int c0 = (tid >> 5) * 256;
        for (int k = c0; k < c0 + 256; k += 8) {
            float4 f0 = *(const float4*)(wrow + k);
            float4 f1 = *(const float4*)(wrow + k + 4);
            fp16x8 v;
            v[0] = (_Float16)f0.x; v[1] = (_Float16)f0.y; v[2] = (_Float16)f0.z; v[3] = (_Float16)f0.w;
            v[4] = (_Float16)f1.x; v[5] = (_Float16)f1.y; v[6] = (_Float16)f1.z; v[7] = (_Float16)f1.w;
            uint32_t byte = (uint32_t)(r * 4096 + k * 2) ^ (uint32_t)((r & 7) << 4);
            *(fp16x8*)(smem + byte) = v;
        }
    }
    __syncthreads();

    float c_state = 0.f;                     // owned by tid<128 (uh=tid&7, ub=tid>>3)
    const int ln15 = lane & 15;
    const int kl   = (lane >> 4) * 8;        // k-offset within 32-chunk (elems)
    const uint32_t sw   = (uint32_t)((ln15 & 7) << 4);
    const uint32_t row0 = (uint32_t)ln15 * 4096u;
    const uint32_t row1 = row0 + 16u * 4096u;
    const int kbase = wave * 512;
    const int uh = tid & 7;
    const int ub = tid >> 3;

    for (int t = 0; t < 128; ++t) {
        // wait: all blocks published h_{t-1} (relaxed agent loads, L3 point)
        while (__hip_atomic_load(flags + tid, __ATOMIC_RELAXED, __HIP_MEMORY_SCOPE_AGENT) < t)
            __builtin_amdgcn_s_sleep(1);
        asm volatile("" ::: "memory");       // no hoisting of h loads above poll
        __syncthreads();

        // prefetch this step's xp slice (independent of h)
        float xi = 0.f, xf = 0.f, xg = 0.f, xo = 0.f;
        if (tid < 128) {
            const float* xpt = xp + (size_t)t * GATES * BATCH;
            const int nb = h0 + uh;
            xi = xpt[((size_t)(0 * HDIM + nb)) * BATCH + ub];
            xf = xpt[((size_t)(1 * HDIM + nb)) * BATCH + ub];
            xg = xpt[((size_t)(2 * HDIM + nb)) * BATCH + ub];
            xo = xpt[((size_t)(3 * HDIM + nb)) * BATCH + ub];
        }

        // load h_{t-1} fragments: 32 x 8B relaxed agent loads (bypass L1/L2),
        // issued as a batch into registers so they pipeline.
        const unsigned long long* hp = (const unsigned long long*)
            (hbuf + (size_t)((t + 1) & 1) * (BATCH * HDIM) + (size_t)ln15 * HDIM + kbase);
        fp16x8 af[16];
#pragma unroll
        for (int s = 0; s < 16; ++s) {
            U8 lo, hi;
            lo.u = __hip_atomic_load(hp + s * 8 + (kl >> 2),     __ATOMIC_RELAXED, __HIP_MEMORY_SCOPE_AGENT);
            hi.u = __hip_atomic_load(hp + s * 8 + (kl >> 2) + 1, __ATOMIC_RELAXED, __HIP_MEMORY_SCOPE_AGENT);
            fp16x8 v;
            v[0] = lo.h4[0]; v[1] = lo.h4[1]; v[2] = lo.h4[2]; v[3] = lo.h4[3];
            v[4] = hi.h4[0]; v[5] = hi.h4[1]; v[6] = hi.h4[2]; v[7] = hi.h4[3];
            af[s] = v;
        }

        f32x4 acc0 = {0.f, 0.f, 0.f, 0.f};
        f32x4 acc1 = {0.f, 0.f, 0.f, 0.f};
#pragma unroll
        for (int s = 0; s < 16; ++s) {
            const uint32_t kb = (uint32_t)((kbase + s * 32 + kl) * 2);
            fp16x8 b0 = *(const fp16x8*)(smem + ((row0 + kb) ^ sw));       // tiles i,f
            fp16x8 b1 = *(const fp16x8*)(smem + ((row1 + kb) ^ sw));       // tiles g,o
            acc0 = __builtin_amdgcn_mfma_f32_16x16x32_f16(af[s], b0, acc0, 0, 0, 0);
            acc1 = __builtin_amdgcn_mfma_f32_16x16x32_f16(af[s], b1, acc1, 0, 0, 0);
        }
        {   // per-wave partials: red[tile][n=ln15][m-batch], padded stride
            float* r0 = red + ((wave * 2 + 0) * 16 + ln15) * RED_STRIDE + (lane >> 4) * 4;
            float* r1 = red + ((wave * 2 + 1) * 16 + ln15) * RED_STRIDE + (lane >> 4) * 4;
#pragma unroll
            for (int i = 0; i < 4; ++i) { r0[i] = acc0[i]; r1[i] = acc1[i]; }
        }
        __syncthreads();

        if (tid < 128) {
            float ip = xi, fp_ = xf, gp = xg, op = xo;
#pragma unroll
            for (int w = 0; w < 4; ++w) {
                ip  += red[((w * 2 + 0) * 16 + uh    ) * RED_STRIDE + ub];
                fp_ += red[((w * 2 + 0) * 16 + uh + 8) * RED_STRIDE + ub];
                gp  += red[((w * 2 + 1) * 16 + uh    ) * RED_STRIDE + ub];
                op  += red[((w * 2 + 1) * 16 + uh + 8) * RED_STRIDE + ub];
            }
            const int nb = h0 + uh;
            float ig = sigmoidf_(ip), fg = sigmoidf_(fp_), og = sigmoidf_(op);
            float gg = tanhf_(gp);
            c_state = fg * c_state + ig * gg;
            float hv = og * tanhf_(c_state);
            HU cv; cv.f = (_Float16)hv;
            // publish h: relaxed agent store (write-through to coherence point)
            __hip_atomic_store(
                (unsigned short*)hbuf + (size_t)(t & 1) * (BATCH * HDIM) + (size_t)ub * HDIM + nb,
                cv.u, __ATOMIC_RELAXED, __HIP_MEMORY_SCOPE_AGENT);
            hseq[((size_t)ub * TSEQ + t) * HDIM + nb] = cv.f;   // normal store
        }
        asm volatile("s_waitcnt vmcnt(0)" ::: "memory");  // each wave drains its stores
        __syncthreads();                                  // all waves drained
        if (tid == 0)
            __hip_atomic_store(flags + blk, t + 1, __ATOMIC_RELAXED, __HIP_MEMORY_SCOPE_AGENT);
    }
}

// ---------------- output projection: out[tok] = h[tok][:]·Wout + bout --------
__global__ __launch_bounds__(256) void outproj_kernel(
        const _Float16* __restrict__ hseq, const float* __restrict__ Wout,
        const float* __restrict__ bout, float* __restrict__ out) {
    const int lane = threadIdx.x & 63;
    const int wave = threadIdx.x >> 6;
    const int tok = blockIdx.x * 4 + wave;
    const _Float16* h = hseq + (size_t)tok * HDIM;
    float acc = 0.f;
#pragma unroll
    for (int c = 0; c < 4; ++c) {
        const int k = c * 512 + lane * 8;
        fp16x8 hv = *(const fp16x8*)(h + k);
        const float* w = Wout + k;
#pragma unroll
        for (int i = 0; i < 8; ++i) acc += (float)hv[i] * w[i];
    }
#pragma unroll
    for (int off = 32; off > 0; off >>= 1) acc += __shfl_down(acc, off, 64);
    if (lane == 0) out[tok] = acc + bout[0];
}

// ---------------- launch -----------------------------------------------------
extern "C" void kernel_launch(void* const* d_in, const int* in_sizes, int n_in,
                              void* d_out, int out_size, void* d_ws, size_t ws_size,
                              hipStream_t stream) {
    (void)in_sizes; (void)n_in; (void)out_size; (void)ws_size;
    const float* x       = (const float*)d_in[0];
    const float* Wih[3]  = {(const float*)d_in[1], (const float*)d_in[5], (const float*)d_in[9]};
    const float* Whh[3]  = {(const float*)d_in[2], (const float*)d_in[6], (const float*)d_in[10]};
    const float* bih[3]  = {(const float*)d_in[3], (const float*)d_in[7], (const float*)d_in[11]};
    const float* bhh[3]  = {(const float*)d_in[4], (const float*)d_in[8], (const float*)d_in[12]};
    const float* Wout    = (const float*)d_in[13];
    const float* bout    = (const float*)d_in[14];
    float* out = (float*)d_out;

    char* ws = (char*)d_ws;
    size_t off = 0;
    auto carve = [&](size_t bytes) {
        char* p = ws + off;
        off += (bytes + 255) & ~(size_t)255;
        return p;
    };
    _Float16* wih16 = (_Float16*)carve((size_t)GATES * 2048 * 2);          // 33.5 MB
    float*    xp    = (float*)   carve((size_t)TSEQ * GATES * BATCH * 4);  // 67 MB
    _Float16* hseqA = (_Float16*)carve((size_t)NTOK * HDIM * 2);           // 8.4 MB
    _Float16* hseqB = (_Float16*)carve((size_t)NTOK * HDIM * 2);           // 8.4 MB
    _Float16* xh    = (_Float16*)carve((size_t)NTOK * 128 * 2);            // 0.5 MB
    _Float16* hbuf  = (_Float16*)carve((size_t)2 * BATCH * HDIM * 2);      // 128 KB
    int*      flags = (int*)     carve(256 * 4);

    hipFuncSetAttribute((const void*)lstm_scan_kernel,
                        hipFuncAttributeMaxDynamicSharedMemorySize, SCAN_LDS_BYTES);

    // x -> fp16
    {
        int n8 = NTOK * 128 / 8;
        cvt_f32_f16_kernel<<<(n8 + 255) / 256, 256, 0, stream>>>(x, xh, n8);
    }

    const _Float16* Ain[3] = {xh, hseqA, hseqB};
    _Float16*       Hout[3] = {hseqA, hseqB, hseqA};
    const int       Kl[3]   = {128, 2048, 2048};

    for (int l = 0; l < 3; ++l) {
        int n8 = GATES * Kl[l] / 8;
        cvt_f32_f16_kernel<<<(n8 + 255) / 256, 256, 0, stream>>>(Wih[l], wih16, n8);
        dim3 ggrid(GATES / 128, NTOK / 128);
        xproj_gemm_kernel<<<ggrid, 256, 0, stream>>>(Ain[l], wih16, bih[l], bhh[l], xp, Kl[l]);
        hipMemsetAsync(flags, 0, 256 * 4, stream);
        hipMemsetAsync(hbuf, 0, (size_t)2 * BATCH * HDIM * 2, stream);
        lstm_scan_kernel<<<256, 256, SCAN_LDS_BYTES, stream>>>(Whh[l], xp, Hout[l], hbuf, flags);
    }
    outproj_kernel<<<NTOK / 4, 256, 0, stream>>>(hseqA, Wout, bout, out);
}

// Round 3
// 3397.868 us; speedup vs baseline: 4.9397x; 1.1606x over previous
//
#include <hip/hip_runtime.h>
#include <hip/hip_fp16.h>
#include <cstdint>
#include <cstddef>

// LSTM 3-layer, H=2048, B=16, T=128, I=128, O=1 (fp32 in/out).
// R3 scan design:
//  - W_hh in REGISTERS (128 VGPR/lane fragments), no LDS weights.
//  - h ring: 129 per-step 64KB slots, layout [kblock=256][batch=16][unit=8] fp16.
//    Producers: write-through agent atomic 8B stores. Consumers: NORMAL cached
//    loads (L2 broadcast tree) — safe because each slot's address is fresh
//    within a launch; cross-replay staleness killed by entry acquire fence.
//  - Role split: waves 0-1 reduce/update/publish; waves 2-3 poll flags
//    concurrently (observe latency hidden). LDS token wave0<->wave1.
//  - xproj GEMM / outproj read the slot ring directly (no hseq buffer).

typedef __attribute__((ext_vector_type(8))) _Float16 fp16x8;
typedef __attribute__((ext_vector_type(4))) float    f32x4;

#define HDIM  2048
#define GATES 8192
#define BATCH 16
#define TSEQ  128
#define NTOK  2048
#define RED_ST 17
#define HSLOT 128               // fp16 per kblock row: 16 batch x 8 units
#define HSTEP_ELEMS 32768       // fp16 per step slot (64KB)

union HU { _Float16 f; unsigned short u; };

__device__ __forceinline__ float sigmoidf_(float x) { return 1.f / (1.f + __expf(-x)); }
__device__ __forceinline__ float tanhf_(float x) {
    float e2 = __expf(2.f * x);
    return 1.f - 2.f / (e2 + 1.f);
}

// ---------------- fp32 -> fp16 conversion (8 elems/thread) -------------------
__global__ __launch_bounds__(256) void cvt_f32_f16_kernel(const float* __restrict__ in,
                                                          _Float16* __restrict__ out, int n8) {
    int i = blockIdx.x * 256 + threadIdx.x;
    if (i >= n8) return;
    const float4* p = (const float4*)in + (size_t)i * 2;
    float4 a = p[0], b = p[1];
    fp16x8 v;
    v[0] = (_Float16)a.x; v[1] = (_Float16)a.y; v[2] = (_Float16)a.z; v[3] = (_Float16)a.w;
    v[4] = (_Float16)b.x; v[5] = (_Float16)b.y; v[6] = (_Float16)b.z; v[7] = (_Float16)b.w;
    ((fp16x8*)out)[i] = v;
}

// ---------------- x_proj GEMM ------------------------------------------------
// A-source: either flat [NTOK][K] fp16 (A) or the h slot ring (Ah != nullptr).
__global__ __launch_bounds__(256) void xproj_gemm_kernel(
        const _Float16* __restrict__ A, const _Float16* __restrict__ Ah,
        const _Float16* __restrict__ W,
        const float* __restrict__ bih, const float* __restrict__ bhh,
        float* __restrict__ xp, int K) {
    __shared__ _Float16 As[128 * 64];
    __shared__ _Float16 Bs[128 * 64];
    const int tid  = threadIdx.x;
    const int lane = tid & 63;
    const int wave = tid >> 6;
    const int n0 = blockIdx.x * 128;
    const int m0 = blockIdx.y * 128;
    const int srow = tid >> 3;
    const int scol = (tid & 7) * 8;
    const int wr = (wave >> 1) * 64;
    const int wc = (wave & 1) * 64;
    const int lr = lane & 15;
    const int lk = (lane >> 4) * 8;

    f32x4 acc[4][4] = {};

    const int nk = K >> 6;
    for (int kt = 0; kt < nk; ++kt) {
        if (kt) __syncthreads();
        const int k0 = kt * 64;
#pragma unroll
        for (int cc = 0; cc < 4; ++cc) {
            const int row = cc * 32 + srow;
            const _Float16* ga;
            if (Ah) {
                const int m = m0 + row, b = m >> 7, tt = m & 127;
                ga = Ah + (size_t)(tt + 1) * HSTEP_ELEMS + (size_t)(k0 + scol) * 16 + b * 8;
            } else {
                ga = A + (size_t)(m0 + row) * K + k0 + scol;
            }
            const _Float16* gb = W + (size_t)(n0 + row) * K + k0 + scol;
            __builtin_amdgcn_global_load_lds(
                (const __attribute__((address_space(1))) void*)ga,
                (__attribute__((address_space(3))) void*)(As + cc * 2048 + wave * 512), 16, 0, 0);
            __builtin_amdgcn_global_load_lds(
                (const __attribute__((address_space(1))) void*)gb,
                (__attribute__((address_space(3))) void*)(Bs + cc * 2048 + wave * 512), 16, 0, 0);
        }
        __syncthreads();
#pragma unroll
        for (int s = 0; s < 2; ++s) {
            fp16x8 af[4], bf[4];
#pragma unroll
            for (int mi = 0; mi < 4; ++mi)
                af[mi] = *(const fp16x8*)(As + (wr + mi * 16 + lr) * 64 + s * 32 + lk);
#pragma unroll
            for (int ni = 0; ni < 4; ++ni)
                bf[ni] = *(const fp16x8*)(Bs + (wc + ni * 16 + lr) * 64 + s * 32 + lk);
#pragma unroll
            for (int mi = 0; mi < 4; ++mi)
#pragma unroll
                for (int ni = 0; ni < 4; ++ni)
                    acc[mi][ni] = __builtin_amdgcn_mfma_f32_16x16x32_f16(
                        af[mi], bf[ni], acc[mi][ni], 0, 0, 0);
        }
    }
    const int rb = (lane >> 4) * 4;
#pragma unroll
    for (int ni = 0; ni < 4; ++ni) {
        const int n = n0 + wc + ni * 16 + lr;
        const float bias = bih[n] + bhh[n];
#pragma unroll
        for (int mi = 0; mi < 4; ++mi) {
#pragma unroll
            for (int r = 0; r < 4; ++r) {
                const int m = m0 + wr + mi * 16 + rb + r;
                const int b = m >> 7, t = m & 127;
                xp[((size_t)t * GATES + n) * BATCH + b] = acc[mi][ni][r] + bias;
            }
        }
    }
}

// ---------------- persistent LSTM scan --------------------------------------
__global__ __launch_bounds__(256, 1) void lstm_scan_kernel(
        const float* __restrict__ Whh,   // [GATES][HDIM] fp32
        const float* __restrict__ xp,    // [TSEQ][GATES][BATCH] fp32
        _Float16* __restrict__ hstep,    // [129][HSTEP_ELEMS] slot ring
        int* __restrict__ flags) {       // [256], zeroed before launch
    // Drop any stale L1/L2 lines from previous replays/layers (once per launch).
    __builtin_amdgcn_fence(__ATOMIC_ACQUIRE, "agent");

    __shared__ float red[8 * 16 * RED_ST];
    __shared__ int tok1;

    const int tid  = threadIdx.x;
    const int lane = tid & 63;
    const int wave = tid >> 6;
    const int blk  = blockIdx.x;
    const int h0   = blk * 8;
    const int ln15 = lane & 15;
    const int kl   = (lane >> 4) * 8;
    const int kbase = wave * 512;

    // ---- W_hh fragments into registers (fp32 -> fp16) ----
    const int rq = ln15 >> 3, rj = ln15 & 7;
    const float* w0 = Whh + ((size_t)rq * HDIM + h0 + rj) * HDIM;          // gates i,f
    const float* w1 = Whh + ((size_t)(rq + 2) * HDIM + h0 + rj) * HDIM;    // gates g,o
    fp16x8 b0[16], b1[16];
#pragma unroll
    for (int s = 0; s < 16; ++s) {
        const int k = kbase + s * 32 + kl;
        float4 a0 = *(const float4*)(w0 + k), a1 = *(const float4*)(w0 + k + 4);
        float4 c0 = *(const float4*)(w1 + k), c1 = *(const float4*)(w1 + k + 4);
        fp16x8 v;
        v[0] = (_Float16)a0.x; v[1] = (_Float16)a0.y; v[2] = (_Float16)a0.z; v[3] = (_Float16)a0.w;
        v[4] = (_Float16)a1.x; v[5] = (_Float16)a1.y; v[6] = (_Float16)a1.z; v[7] = (_Float16)a1.w;
        b0[s] = v;
        v[0] = (_Float16)c0.x; v[1] = (_Float16)c0.y; v[2] = (_Float16)c0.z; v[3] = (_Float16)c0.w;
        v[4] = (_Float16)c1.x; v[5] = (_Float16)c1.y; v[6] = (_Float16)c1.z; v[7] = (_Float16)c1.w;
        b1[s] = v;
    }
    if (tid == 0) tok1 = 0;
    float c_state = 0.f;
    const int uh = tid & 7, ub = tid >> 3;   // update thread: unit uh, batch ub
    __syncthreads();

    for (int t = 0; t < TSEQ; ++t) {
        asm volatile("" ::: "memory");       // no load hoisting above barrier
        const _Float16* hsrc = hstep + (size_t)t * HSTEP_ELEMS;

        float xi = 0.f, xf = 0.f, xg = 0.f, xo = 0.f;
        if (tid < 128) {                     // xp prefetch (independent of h)
            const float* xpt = xp + (size_t)t * GATES * BATCH;
            const int nb = h0 + uh;
            xi = xpt[(size_t)(0 * HDIM + nb) * BATCH + ub];
            xf = xpt[(size_t)(1 * HDIM + nb) * BATCH + ub];
            xg = xpt[(size_t)(2 * HDIM + nb) * BATCH + ub];
            xo = xpt[(size_t)(3 * HDIM + nb) * BATCH + ub];
        }

        // h_{t-1} fragments: normal cached loads (L2 broadcast tree)
        fp16x8 af[16];
#pragma unroll
        for (int s = 0; s < 16; ++s) {
            const int k = kbase + s * 32 + kl;
            af[s] = *(const fp16x8*)(hsrc + (size_t)k * 16 + ln15 * 8);
        }

        f32x4 acc0 = {0.f, 0.f, 0.f, 0.f};
        f32x4 acc1 = {0.f, 0.f, 0.f, 0.f};
#pragma unroll
        for (int s = 0; s < 16; ++s) {
            acc0 = __builtin_amdgcn_mfma_f32_16x16x32_f16(af[s], b0[s], acc0, 0, 0, 0);
            acc1 = __builtin_amdgcn_mfma_f32_16x16x32_f16(af[s], b1[s], acc1, 0, 0, 0);
        }
        {
            float* r0 = red + ((wave * 2 + 0) * 16 + ln15) * RED_ST + (lane >> 4) * 4;
            float* r1 = red + ((wave * 2 + 1) * 16 + ln15) * RED_ST + (lane >> 4) * 4;
#pragma unroll
            for (int i = 0; i < 4; ++i) { r0[i] = acc0[i]; r1[i] = acc1[i]; }
        }
        __syncthreads();                     // b2: partials visible
        asm volatile("" ::: "memory");

        if (tid < 128) {
            // ---- reduce + gate math + publish (waves 0-1) ----
            float ip = xi, fp_ = xf, gp = xg, op = xo;
#pragma unroll
            for (int w = 0; w < 4; ++w) {
                ip  += red[((w * 2 + 0) * 16 + uh    ) * RED_ST + ub];
                fp_ += red[((w * 2 + 0) * 16 + uh + 8) * RED_ST + ub];
                gp  += red[((w * 2 + 1) * 16 + uh    ) * RED_ST + ub];
                op  += red[((w * 2 + 1) * 16 + uh + 8) * RED_ST + ub];
            }
            float ig = sigmoidf_(ip), fg = sigmoidf_(fp_), og = sigmoidf_(op);
            float gg = tanhf_(gp);
            c_state = fg * c_state + ig * gg;
            float hv = og * tanhf_(c_state);
            HU cv; cv.f = (_Float16)hv;
            unsigned v  = cv.u;
            unsigned v1 = __shfl_down(v, 1, 64);
            unsigned v2 = __shfl_down(v, 2, 64);
            unsigned v3 = __shfl_down(v, 3, 64);
            if ((tid & 3) == 0) {            // pack 4 units -> 8B write-through store
                unsigned long long pk = (unsigned long long)v
                                      | ((unsigned long long)v1 << 16)
                                      | ((unsigned long long)v2 << 32)
                                      | ((unsigned long long)v3 << 48);
                unsigned long long* dst = (unsigned long long*)
                    (hstep + (size_t)(t + 1) * HSTEP_ELEMS + blk * HSLOT + ub * 8 + uh);
                __hip_atomic_store(dst, pk, __ATOMIC_RELAXED, __HIP_MEMORY_SCOPE_AGENT);
            }
            if (t < TSEQ - 1) {
                asm volatile("s_waitcnt vmcnt(0)" ::: "memory");   // own stores at L3
                if (wave == 1) {
                    if (lane == 0)
                        __hip_atomic_store(&tok1, t + 1, __ATOMIC_RELEASE, __HIP_MEMORY_SCOPE_WORKGROUP);
                } else if (lane == 0) {
                    while (__hip_atomic_load(&tok1, __ATOMIC_ACQUIRE, __HIP_MEMORY_SCOPE_WORKGROUP) < t + 1) {}
                    __hip_atomic_store(flags + blk, t + 1, __ATOMIC_RELAXED, __HIP_MEMORY_SCOPE_AGENT);
                }
            }
        } else if (t < TSEQ - 1) {
            // ---- waves 2-3: poll all blocks' step-t flags (overlapped) ----
            const int j0 = tid - 128, j1 = tid;
            bool d0 = (j0 == blk), d1 = (j1 == blk);
            while (!(d0 && d1)) {
                if (!d0) d0 = __hip_atomic_load(flags + j0, __ATOMIC_RELAXED, __HIP_MEMORY_SCOPE_AGENT) > t;
                if (!d1) d1 = __hip_atomic_load(flags + j1, __ATOMIC_RELAXED, __HIP_MEMORY_SCOPE_AGENT) > t;
                if (!(d0 && d1)) __builtin_amdgcn_s_sleep(1);
            }
        }
        __syncthreads();                     // b1: h_t globally available
    }
}

// ---------------- output projection -----------------------------------------
__global__ __launch_bounds__(256) void outproj_kernel(
        const _Float16* __restrict__ hstep, const float* __restrict__ Wout,
        const float* __restrict__ bout, float* __restrict__ out) {
    const int lane = threadIdx.x & 63;
    const int wave = threadIdx.x >> 6;
    const int tok = blockIdx.x * 4 + wave;
    const int b = tok >> 7, t = tok & 127;
    const _Float16* h = hstep + (size_t)(t + 1) * HSTEP_ELEMS + b * 8;
    float acc = 0.f;
#pragma unroll
    for (int c = 0; c < 4; ++c) {
        const int k = c * 512 + lane * 8;
        fp16x8 hv = *(const fp16x8*)(h + (size_t)k * 16);
        const float* w = Wout + k;
#pragma unroll
        for (int i = 0; i < 8; ++i) acc += (float)hv[i] * w[i];
    }
#pragma unroll
    for (int off = 32; off > 0; off >>= 1) acc += __shfl_down(acc, off, 64);
    if (lane == 0) out[tok] = acc + bout[0];
}

// ---------------- launch -----------------------------------------------------
extern "C" void kernel_launch(void* const* d_in, const int* in_sizes, int n_in,
                              void* d_out, int out_size, void* d_ws, size_t ws_size,
                              hipStream_t stream) {
    (void)in_sizes; (void)n_in; (void)out_size; (void)ws_size;
    const float* x       = (const float*)d_in[0];
    const float* Wih[3]  = {(const float*)d_in[1], (const float*)d_in[5], (const float*)d_in[9]};
    const float* Whh[3]  = {(const float*)d_in[2], (const float*)d_in[6], (const float*)d_in[10]};
    const float* bih[3]  = {(const float*)d_in[3], (const float*)d_in[7], (const float*)d_in[11]};
    const float* bhh[3]  = {(const float*)d_in[4], (const float*)d_in[8], (const float*)d_in[12]};
    const float* Wout    = (const float*)d_in[13];
    const float* bout    = (const float*)d_in[14];
    float* out = (float*)d_out;

    char* ws = (char*)d_ws;
    size_t off = 0;
    auto carve = [&](size_t bytes) {
        char* p = ws + off;
        off += (bytes + 255) & ~(size_t)255;
        return p;
    };
    _Float16* wih16 = (_Float16*)carve((size_t)GATES * 2048 * 2);           // 33.5 MB
    float*    xp    = (float*)   carve((size_t)TSEQ * GATES * BATCH * 4);   // 67 MB
    _Float16* xh    = (_Float16*)carve((size_t)NTOK * 128 * 2);             // 0.5 MB
    _Float16* hstep = (_Float16*)carve((size_t)(TSEQ + 1) * HSTEP_ELEMS * 2); // 8.46 MB
    int*      flags = (int*)     carve(256 * 4);

    {   // x -> fp16
        int n8 = NTOK * 128 / 8;
        cvt_f32_f16_kernel<<<(n8 + 255) / 256, 256, 0, stream>>>(x, xh, n8);
    }

    const int Kl[3] = {128, 2048, 2048};
    for (int l = 0; l < 3; ++l) {
        int n8 = GATES * Kl[l] / 8;
        cvt_f32_f16_kernel<<<(n8 + 255) / 256, 256, 0, stream>>>(Wih[l], wih16, n8);
        dim3 ggrid(GATES / 128, NTOK / 128);
        xproj_gemm_kernel<<<ggrid, 256, 0, stream>>>(
            l == 0 ? xh : nullptr, l == 0 ? nullptr : hstep,
            wih16, bih[l], bhh[l], xp, Kl[l]);
        hipMemsetAsync(flags, 0, 256 * 4, stream);
        hipMemsetAsync(hstep, 0, HSTEP_ELEMS * 2, stream);   // slot 0 = h_{-1} = 0
        lstm_scan_kernel<<<256, 256, 0, stream>>>(Whh[l], xp, hstep, flags);
    }
    outproj_kernel<<<NTOK / 4, 256, 0, stream>>>(hstep, Wout, bout, out);
}

// Round 4
// 2464.518 us; speedup vs baseline: 6.8104x; 1.3787x over previous
//
#include <hip/hip_runtime.h>
#include <hip/hip_fp16.h>
#include <cstdint>
#include <cstddef>

// LSTM 3-layer, H=2048, B=16, T=128, I=128, O=1 (fp32 in/out).
// R4 scan design:
//  - W_hh in registers (128 VGPR/lane), h slot ring (129 x 64KB) with
//    write-through agent-atomic producer stores + normal cached consumer loads
//    (entry agent-acquire fence kills cross-launch staleness).
//  - Flag fabric: per-wave source-set polling (wave w polls exactly its 64
//    producer blocks, 1 flag/lane), flags on 64B-stride lines, 4 replicas
//    (block polls replica blk&3)  ->  ~64 pollers/line, no L3 serialization.
//  - Monotonic flag values (flag_base = 128*layer): memset once per launch.
//  - Double-buffered red partials (parity t&1): ONE barrier per step.
//  - xp[t+1] prefetched into registers after publish (off critical path).

typedef __attribute__((ext_vector_type(8))) _Float16 fp16x8;
typedef __attribute__((ext_vector_type(4))) float    f32x4;

#define HDIM  2048
#define GATES 8192
#define BATCH 16
#define TSEQ  128
#define NTOK  2048
#define RED_ST 17
#define HSLOT 128               // fp16 per kblock row: 16 batch x 8 units
#define HSTEP_ELEMS 32768       // fp16 per step slot (64KB)
#define FLAG_STRIDE 16          // ints: 64B per flag line
#define NFLAG_COPY 4

union HU { _Float16 f; unsigned short u; };

__device__ __forceinline__ float sigmoidf_(float x) { return 1.f / (1.f + __expf(-x)); }
__device__ __forceinline__ float tanhf_(float x) {
    float e2 = __expf(2.f * x);
    return 1.f - 2.f / (e2 + 1.f);
}

// ---------------- fp32 -> fp16 conversion (8 elems/thread) -------------------
__global__ __launch_bounds__(256) void cvt_f32_f16_kernel(const float* __restrict__ in,
                                                          _Float16* __restrict__ out, int n8) {
    int i = blockIdx.x * 256 + threadIdx.x;
    if (i >= n8) return;
    const float4* p = (const float4*)in + (size_t)i * 2;
    float4 a = p[0], b = p[1];
    fp16x8 v;
    v[0] = (_Float16)a.x; v[1] = (_Float16)a.y; v[2] = (_Float16)a.z; v[3] = (_Float16)a.w;
    v[4] = (_Float16)b.x; v[5] = (_Float16)b.y; v[6] = (_Float16)b.z; v[7] = (_Float16)b.w;
    ((fp16x8*)out)[i] = v;
}

// ---------------- x_proj GEMM ------------------------------------------------
// A-source: either flat [NTOK][K] fp16 (A) or the h slot ring (Ah != nullptr).
__global__ __launch_bounds__(256) void xproj_gemm_kernel(
        const _Float16* __restrict__ A, const _Float16* __restrict__ Ah,
        const _Float16* __restrict__ W,
        const float* __restrict__ bih, const float* __restrict__ bhh,
        float* __restrict__ xp, int K) {
    __shared__ _Float16 As[128 * 64];
    __shared__ _Float16 Bs[128 * 64];
    const int tid  = threadIdx.x;
    const int lane = tid & 63;
    const int wave = tid >> 6;
    const int n0 = blockIdx.x * 128;
    const int m0 = blockIdx.y * 128;
    const int srow = tid >> 3;
    const int scol = (tid & 7) * 8;
    const int wr = (wave >> 1) * 64;
    const int wc = (wave & 1) * 64;
    const int lr = lane & 15;
    const int lk = (lane >> 4) * 8;

    f32x4 acc[4][4] = {};

    const int nk = K >> 6;
    for (int kt = 0; kt < nk; ++kt) {
        if (kt) __syncthreads();
        const int k0 = kt * 64;
#pragma unroll
        for (int cc = 0; cc < 4; ++cc) {
            const int row = cc * 32 + srow;
            const _Float16* ga;
            if (Ah) {
                const int m = m0 + row, b = m >> 7, tt = m & 127;
                ga = Ah + (size_t)(tt + 1) * HSTEP_ELEMS + (size_t)(k0 + scol) * 16 + b * 8;
            } else {
                ga = A + (size_t)(m0 + row) * K + k0 + scol;
            }
            const _Float16* gb = W + (size_t)(n0 + row) * K + k0 + scol;
            __builtin_amdgcn_global_load_lds(
                (const __attribute__((address_space(1))) void*)ga,
                (__attribute__((address_space(3))) void*)(As + cc * 2048 + wave * 512), 16, 0, 0);
            __builtin_amdgcn_global_load_lds(
                (const __attribute__((address_space(1))) void*)gb,
                (__attribute__((address_space(3))) void*)(Bs + cc * 2048 + wave * 512), 16, 0, 0);
        }
        __syncthreads();
#pragma unroll
        for (int s = 0; s < 2; ++s) {
            fp16x8 af[4], bf[4];
#pragma unroll
            for (int mi = 0; mi < 4; ++mi)
                af[mi] = *(const fp16x8*)(As + (wr + mi * 16 + lr) * 64 + s * 32 + lk);
#pragma unroll
            for (int ni = 0; ni < 4; ++ni)
                bf[ni] = *(const fp16x8*)(Bs + (wc + ni * 16 + lr) * 64 + s * 32 + lk);
#pragma unroll
            for (int mi = 0; mi < 4; ++mi)
#pragma unroll
                for (int ni = 0; ni < 4; ++ni)
                    acc[mi][ni] = __builtin_amdgcn_mfma_f32_16x16x32_f16(
                        af[mi], bf[ni], acc[mi][ni], 0, 0, 0);
        }
    }
    const int rb = (lane >> 4) * 4;
#pragma unroll
    for (int ni = 0; ni < 4; ++ni) {
        const int n = n0 + wc + ni * 16 + lr;
        const float bias = bih[n] + bhh[n];
#pragma unroll
        for (int mi = 0; mi < 4; ++mi) {
#pragma unroll
            for (int r = 0; r < 4; ++r) {
                const int m = m0 + wr + mi * 16 + rb + r;
                const int b = m >> 7, t = m & 127;
                xp[((size_t)t * GATES + n) * BATCH + b] = acc[mi][ni][r] + bias;
            }
        }
    }
}

// ---------------- persistent LSTM scan --------------------------------------
__global__ __launch_bounds__(256, 1) void lstm_scan_kernel(
        const float* __restrict__ Whh,   // [GATES][HDIM] fp32
        const float* __restrict__ xp,    // [TSEQ][GATES][BATCH] fp32
        _Float16* __restrict__ hstep,    // [129][HSTEP_ELEMS] slot ring
        int* __restrict__ flags,         // [NFLAG_COPY][256][FLAG_STRIDE]
        int flag_base) {
    // Drop stale L1/L2 lines from previous launches/replays (once per launch).
    __builtin_amdgcn_fence(__ATOMIC_ACQUIRE, "agent");

    __shared__ float red[2][8 * 16 * RED_ST];
    __shared__ int tok1;

    const int tid  = threadIdx.x;
    const int lane = tid & 63;
    const int wave = tid >> 6;
    const int blk  = blockIdx.x;
    const int h0   = blk * 8;
    const int ln15 = lane & 15;
    const int kl   = (lane >> 4) * 8;
    const int kbase = wave * 512;

    // ---- W_hh fragments into registers (fp32 -> fp16) ----
    const int rq = ln15 >> 3, rj = ln15 & 7;
    const float* w0 = Whh + ((size_t)rq * HDIM + h0 + rj) * HDIM;          // gates i,f
    const float* w1 = Whh + ((size_t)(rq + 2) * HDIM + h0 + rj) * HDIM;    // gates g,o
    fp16x8 b0[16], b1[16];
#pragma unroll
    for (int s = 0; s < 16; ++s) {
        const int k = kbase + s * 32 + kl;
        float4 a0 = *(const float4*)(w0 + k), a1 = *(const float4*)(w0 + k + 4);
        float4 c0 = *(const float4*)(w1 + k), c1 = *(const float4*)(w1 + k + 4);
        fp16x8 v;
        v[0] = (_Float16)a0.x; v[1] = (_Float16)a0.y; v[2] = (_Float16)a0.z; v[3] = (_Float16)a0.w;
        v[4] = (_Float16)a1.x; v[5] = (_Float16)a1.y; v[6] = (_Float16)a1.z; v[7] = (_Float16)a1.w;
        b0[s] = v;
        v[0] = (_Float16)c0.x; v[1] = (_Float16)c0.y; v[2] = (_Float16)c0.z; v[3] = (_Float16)c0.w;
        v[4] = (_Float16)c1.x; v[5] = (_Float16)c1.y; v[6] = (_Float16)c1.z; v[7] = (_Float16)c1.w;
        b1[s] = v;
    }
    if (tid == 0) tok1 = flag_base;
    float c_state = 0.f;
    const int uh = tid & 7, ub = tid >> 3;   // update thread: unit uh, batch ub

    // wave w consumes k-chunk from blocks [64w, 64w+64): poll 1 flag per lane,
    // replica blk&3 (each flag line has ~64 pollers device-wide).
    const int* fl = flags + (size_t)(((blk & 3) << 8) | (wave << 6) | lane) * FLAG_STRIDE;

    // xp prefetch for t=0
    float xi = 0.f, xf = 0.f, xg = 0.f, xo = 0.f;
    if (tid < 128) {
        const int nb = h0 + uh;
        xi = xp[(size_t)(0 * HDIM + nb) * BATCH + ub];
        xf = xp[(size_t)(1 * HDIM + nb) * BATCH + ub];
        xg = xp[(size_t)(2 * HDIM + nb) * BATCH + ub];
        xo = xp[(size_t)(3 * HDIM + nb) * BATCH + ub];
    }
    __syncthreads();

    for (int t = 0; t < TSEQ; ++t) {
        if (t) {   // wait: my 64 producer blocks published h_{t-1}
            while (__hip_atomic_load(fl, __ATOMIC_RELAXED, __HIP_MEMORY_SCOPE_AGENT)
                   < flag_base + t)
                __builtin_amdgcn_s_sleep(1);
        }
        asm volatile("" ::: "memory");       // no load hoisting above poll
        const _Float16* hsrc = hstep + (size_t)t * HSTEP_ELEMS;

        fp16x8 af[16];
#pragma unroll
        for (int s = 0; s < 16; ++s) {
            const int k = kbase + s * 32 + kl;
            af[s] = *(const fp16x8*)(hsrc + (size_t)k * 16 + ln15 * 8);
        }

        f32x4 acc0 = {0.f, 0.f, 0.f, 0.f};
        f32x4 acc1 = {0.f, 0.f, 0.f, 0.f};
#pragma unroll
        for (int s = 0; s < 16; ++s) {
            acc0 = __builtin_amdgcn_mfma_f32_16x16x32_f16(af[s], b0[s], acc0, 0, 0, 0);
            acc1 = __builtin_amdgcn_mfma_f32_16x16x32_f16(af[s], b1[s], acc1, 0, 0, 0);
        }
        {
            float* r0 = red[t & 1] + ((wave * 2 + 0) * 16 + ln15) * RED_ST + (lane >> 4) * 4;
            float* r1 = red[t & 1] + ((wave * 2 + 1) * 16 + ln15) * RED_ST + (lane >> 4) * 4;
#pragma unroll
            for (int i = 0; i < 4; ++i) { r0[i] = acc0[i]; r1[i] = acc1[i]; }
        }
        __syncthreads();                     // the single per-step barrier
        asm volatile("" ::: "memory");

        if (tid < 128) {
            const float* redp = red[t & 1];
            float ip = xi, fp_ = xf, gp = xg, op = xo;
#pragma unroll
            for (int w = 0; w < 4; ++w) {
                ip  += redp[((w * 2 + 0) * 16 + uh    ) * RED_ST + ub];
                fp_ += redp[((w * 2 + 0) * 16 + uh + 8) * RED_ST + ub];
                gp  += redp[((w * 2 + 1) * 16 + uh    ) * RED_ST + ub];
                op  += redp[((w * 2 + 1) * 16 + uh + 8) * RED_ST + ub];
            }
            float ig = sigmoidf_(ip), fg = sigmoidf_(fp_), og = sigmoidf_(op);
            float gg = tanhf_(gp);
            c_state = fg * c_state + ig * gg;
            float hv = og * tanhf_(c_state);
            HU cv; cv.f = (_Float16)hv;
            unsigned v  = cv.u;
            unsigned v1 = __shfl_down(v, 1, 64);
            unsigned v2 = __shfl_down(v, 2, 64);
            unsigned v3 = __shfl_down(v, 3, 64);
            if ((tid & 3) == 0) {            // pack 4 units -> 8B write-through store
                unsigned long long pk = (unsigned long long)v
                                      | ((unsigned long long)v1 << 16)
                                      | ((unsigned long long)v2 << 32)
                                      | ((unsigned long long)v3 << 48);
                unsigned long long* dst = (unsigned long long*)
                    (hstep + (size_t)(t + 1) * HSTEP_ELEMS + blk * HSLOT + ub * 8 + uh);
                __hip_atomic_store(dst, pk, __ATOMIC_RELAXED, __HIP_MEMORY_SCOPE_AGENT);
            }
            if (t < TSEQ - 1) {
                asm volatile("s_waitcnt vmcnt(0)" ::: "memory");   // own h stores at L3
                if (wave == 1) {
                    if (lane == 0)
                        __hip_atomic_store(&tok1, flag_base + t + 1,
                                           __ATOMIC_RELEASE, __HIP_MEMORY_SCOPE_WORKGROUP);
                } else if (lane == 0) {
                    while (__hip_atomic_load(&tok1, __ATOMIC_ACQUIRE,
                                             __HIP_MEMORY_SCOPE_WORKGROUP) < flag_base + t + 1) {}
#pragma unroll
                    for (int c = 0; c < NFLAG_COPY; ++c)
                        __hip_atomic_store(flags + (size_t)((c << 8) | blk) * FLAG_STRIDE,
                                           flag_base + t + 1,
                                           __ATOMIC_RELAXED, __HIP_MEMORY_SCOPE_AGENT);
                }
                // prefetch xp[t+1] (latency hides under next step's poll)
                const float* xpt = xp + (size_t)(t + 1) * GATES * BATCH;
                const int nb = h0 + uh;
                xi = xpt[(size_t)(0 * HDIM + nb) * BATCH + ub];
                xf = xpt[(size_t)(1 * HDIM + nb) * BATCH + ub];
                xg = xpt[(size_t)(2 * HDIM + nb) * BATCH + ub];
                xo = xpt[(size_t)(3 * HDIM + nb) * BATCH + ub];
            }
        }
    }
}

// ---------------- output projection -----------------------------------------
__global__ __launch_bounds__(256) void outproj_kernel(
        const _Float16* __restrict__ hstep, const float* __restrict__ Wout,
        const float* __restrict__ bout, float* __restrict__ out) {
    const int lane = threadIdx.x & 63;
    const int wave = threadIdx.x >> 6;
    const int tok = blockIdx.x * 4 + wave;
    const int b = tok >> 7, t = tok & 127;
    const _Float16* h = hstep + (size_t)(t + 1) * HSTEP_ELEMS + b * 8;
    float acc = 0.f;
#pragma unroll
    for (int c = 0; c < 4; ++c) {
        const int k = c * 512 + lane * 8;
        fp16x8 hv = *(const fp16x8*)(h + (size_t)k * 16);
        const float* w = Wout + k;
#pragma unroll
        for (int i = 0; i < 8; ++i) acc += (float)hv[i] * w[i];
    }
#pragma unroll
    for (int off = 32; off > 0; off >>= 1) acc += __shfl_down(acc, off, 64);
    if (lane == 0) out[tok] = acc + bout[0];
}

// ---------------- launch -----------------------------------------------------
extern "C" void kernel_launch(void* const* d_in, const int* in_sizes, int n_in,
                              void* d_out, int out_size, void* d_ws, size_t ws_size,
                              hipStream_t stream) {
    (void)in_sizes; (void)n_in; (void)out_size; (void)ws_size;
    const float* x       = (const float*)d_in[0];
    const float* Wih[3]  = {(const float*)d_in[1], (const float*)d_in[5], (const float*)d_in[9]};
    const float* Whh[3]  = {(const float*)d_in[2], (const float*)d_in[6], (const float*)d_in[10]};
    const float* bih[3]  = {(const float*)d_in[3], (const float*)d_in[7], (const float*)d_in[11]};
    const float* bhh[3]  = {(const float*)d_in[4], (const float*)d_in[8], (const float*)d_in[12]};
    const float* Wout    = (const float*)d_in[13];
    const float* bout    = (const float*)d_in[14];
    float* out = (float*)d_out;

    char* ws = (char*)d_ws;
    size_t off = 0;
    auto carve = [&](size_t bytes) {
        char* p = ws + off;
        off += (bytes + 255) & ~(size_t)255;
        return p;
    };
    _Float16* wih16 = (_Float16*)carve((size_t)GATES * 2048 * 2);             // 33.5 MB
    float*    xp    = (float*)   carve((size_t)TSEQ * GATES * BATCH * 4);     // 67 MB
    _Float16* xh    = (_Float16*)carve((size_t)NTOK * 128 * 2);               // 0.5 MB
    _Float16* hstep = (_Float16*)carve((size_t)(TSEQ + 1) * HSTEP_ELEMS * 2); // 8.46 MB
    int*      flags = (int*)     carve((size_t)NFLAG_COPY * 256 * FLAG_STRIDE * 4); // 64 KB

    // one-time init (captured in graph, re-runs each replay)
    hipMemsetAsync(flags, 0, (size_t)NFLAG_COPY * 256 * FLAG_STRIDE * 4, stream);
    hipMemsetAsync(hstep, 0, HSTEP_ELEMS * 2, stream);   // slot 0 = h_{-1} = 0

    {   // x -> fp16
        int n8 = NTOK * 128 / 8;
        cvt_f32_f16_kernel<<<(n8 + 255) / 256, 256, 0, stream>>>(x, xh, n8);
    }

    const int Kl[3] = {128, 2048, 2048};
    for (int l = 0; l < 3; ++l) {
        int n8 = GATES * Kl[l] / 8;
        cvt_f32_f16_kernel<<<(n8 + 255) / 256, 256, 0, stream>>>(Wih[l], wih16, n8);
        dim3 ggrid(GATES / 128, NTOK / 128);
        xproj_gemm_kernel<<<ggrid, 256, 0, stream>>>(
            l == 0 ? xh : nullptr, l == 0 ? nullptr : hstep,
            wih16, bih[l], bhh[l], xp, Kl[l]);
        lstm_scan_kernel<<<256, 256, 0, stream>>>(Whh[l], xp, hstep, flags, l * TSEQ);
    }
    outproj_kernel<<<NTOK / 4, 256, 0, stream>>>(hstep, Wout, bout, out);
}

// Round 5
// 1728.059 us; speedup vs baseline: 9.7129x; 1.4262x over previous
//
#include <hip/hip_runtime.h>
#include <hip/hip_fp16.h>
#include <cstdint>
#include <cstddef>

// LSTM 3-layer, H=2048, B=16, T=128, I=128, O=1 (fp32 in/out).
// R5 changes vs R4 (all on the scan critical path + GEMM epilogue):
//  - xp[t] loads issued at TOP of step t, AFTER af loads (in-order vmcnt:
//    af's counted wait excludes them; barrier drains them; the next poll's
//    vmcnt(0) no longer eats xp latency).  [R4 rock #1]
//  - Dual flag arrays fa/fb (wave0/wave1 publish independently after own
//    vmcnt(0)) — removes the LDS tok1 handshake.  [rock #2]
//  - 4 MFMA accumulator chains (even/odd k) merged before red write. [rock #3]
//  - Poll loop tightened (no s_sleep).
//  - xp layout [t][b][8192]: GEMM epilogue stores are 64B-coalesced per
//    16-lane group (was 4B-per-line scatter = 16x write amplification).

typedef __attribute__((ext_vector_type(8))) _Float16 fp16x8;
typedef __attribute__((ext_vector_type(4))) float    f32x4;

#define HDIM  2048
#define GATES 8192
#define BATCH 16
#define TSEQ  128
#define NTOK  2048
#define RED_ST 17
#define HSLOT 128               // fp16 per kblock row: 16 batch x 8 units
#define HSTEP_ELEMS 32768       // fp16 per step slot (64KB)
#define FLAG_STRIDE 16          // ints: 64B per flag line
#define NFLAG_COPY 4
#define FB_OFF (NFLAG_COPY * 256 * FLAG_STRIDE)   // second flag array offset (ints)

union HU { _Float16 f; unsigned short u; };

__device__ __forceinline__ float sigmoidf_(float x) { return 1.f / (1.f + __expf(-x)); }
__device__ __forceinline__ float tanhf_(float x) {
    float e2 = __expf(2.f * x);
    return 1.f - 2.f / (e2 + 1.f);
}

// ---------------- fp32 -> fp16 conversion (8 elems/thread) -------------------
__global__ __launch_bounds__(256) void cvt_f32_f16_kernel(const float* __restrict__ in,
                                                          _Float16* __restrict__ out, int n8) {
    int i = blockIdx.x * 256 + threadIdx.x;
    if (i >= n8) return;
    const float4* p = (const float4*)in + (size_t)i * 2;
    float4 a = p[0], b = p[1];
    fp16x8 v;
    v[0] = (_Float16)a.x; v[1] = (_Float16)a.y; v[2] = (_Float16)a.z; v[3] = (_Float16)a.w;
    v[4] = (_Float16)b.x; v[5] = (_Float16)b.y; v[6] = (_Float16)b.z; v[7] = (_Float16)b.w;
    ((fp16x8*)out)[i] = v;
}

// ---------------- x_proj GEMM ------------------------------------------------
// A-source: flat [NTOK][K] fp16 (A) or h slot ring (Ah != nullptr).
// Output: xp[t][b][n] fp32 (n contiguous -> coalesced epilogue stores).
__global__ __launch_bounds__(256) void xproj_gemm_kernel(
        const _Float16* __restrict__ A, const _Float16* __restrict__ Ah,
        const _Float16* __restrict__ W,
        const float* __restrict__ bih, const float* __restrict__ bhh,
        float* __restrict__ xp, int K) {
    __shared__ _Float16 As[128 * 64];
    __shared__ _Float16 Bs[128 * 64];
    const int tid  = threadIdx.x;
    const int lane = tid & 63;
    const int wave = tid >> 6;
    const int n0 = blockIdx.x * 128;
    const int m0 = blockIdx.y * 128;
    const int srow = tid >> 3;
    const int scol = (tid & 7) * 8;
    const int wr = (wave >> 1) * 64;
    const int wc = (wave & 1) * 64;
    const int lr = lane & 15;
    const int lk = (lane >> 4) * 8;

    f32x4 acc[4][4] = {};

    const int nk = K >> 6;
    for (int kt = 0; kt < nk; ++kt) {
        if (kt) __syncthreads();
        const int k0 = kt * 64;
#pragma unroll
        for (int cc = 0; cc < 4; ++cc) {
            const int row = cc * 32 + srow;
            const _Float16* ga;
            if (Ah) {
                const int m = m0 + row, b = m >> 7, tt = m & 127;
                ga = Ah + (size_t)(tt + 1) * HSTEP_ELEMS + (size_t)(k0 + scol) * 16 + b * 8;
            } else {
                ga = A + (size_t)(m0 + row) * K + k0 + scol;
            }
            const _Float16* gb = W + (size_t)(n0 + row) * K + k0 + scol;
            __builtin_amdgcn_global_load_lds(
                (const __attribute__((address_space(1))) void*)ga,
                (__attribute__((address_space(3))) void*)(As + cc * 2048 + wave * 512), 16, 0, 0);
            __builtin_amdgcn_global_load_lds(
                (const __attribute__((address_space(1))) void*)gb,
                (__attribute__((address_space(3))) void*)(Bs + cc * 2048 + wave * 512), 16, 0, 0);
        }
        __syncthreads();
#pragma unroll
        for (int s = 0; s < 2; ++s) {
            fp16x8 af[4], bf[4];
#pragma unroll
            for (int mi = 0; mi < 4; ++mi)
                af[mi] = *(const fp16x8*)(As + (wr + mi * 16 + lr) * 64 + s * 32 + lk);
#pragma unroll
            for (int ni = 0; ni < 4; ++ni)
                bf[ni] = *(const fp16x8*)(Bs + (wc + ni * 16 + lr) * 64 + s * 32 + lk);
#pragma unroll
            for (int mi = 0; mi < 4; ++mi)
#pragma unroll
                for (int ni = 0; ni < 4; ++ni)
                    acc[mi][ni] = __builtin_amdgcn_mfma_f32_16x16x32_f16(
                        af[mi], bf[ni], acc[mi][ni], 0, 0, 0);
        }
    }
    const int rb = (lane >> 4) * 4;
#pragma unroll
    for (int ni = 0; ni < 4; ++ni) {
        const int n = n0 + wc + ni * 16 + lr;
        const float bias = bih[n] + bhh[n];
#pragma unroll
        for (int mi = 0; mi < 4; ++mi) {
#pragma unroll
            for (int r = 0; r < 4; ++r) {
                const int m = m0 + wr + mi * 16 + rb + r;
                const int b = m >> 7, t = m & 127;
                xp[((size_t)t * BATCH + b) * GATES + n] = acc[mi][ni][r] + bias;
            }
        }
    }
}

// ---------------- persistent LSTM scan --------------------------------------
__global__ __launch_bounds__(256, 1) void lstm_scan_kernel(
        const float* __restrict__ Whh,   // [GATES][HDIM] fp32
        const float* __restrict__ xp,    // [TSEQ][BATCH][GATES] fp32
        _Float16* __restrict__ hstep,    // [129][HSTEP_ELEMS] slot ring
        int* __restrict__ flags,         // [2][NFLAG_COPY][256][FLAG_STRIDE]
        int flag_base) {
    // Drop stale L1/L2 lines from previous launches/replays (once per launch).
    __builtin_amdgcn_fence(__ATOMIC_ACQUIRE, "agent");

    __shared__ float red[2][8 * 16 * RED_ST];

    const int tid  = threadIdx.x;
    const int lane = tid & 63;
    const int wave = tid >> 6;
    const int blk  = blockIdx.x;
    const int h0   = blk * 8;
    const int ln15 = lane & 15;
    const int kl   = (lane >> 4) * 8;
    const int kbase = wave * 512;

    // ---- W_hh fragments into registers (fp32 -> fp16) ----
    const int rq = ln15 >> 3, rj = ln15 & 7;
    const float* w0 = Whh + ((size_t)rq * HDIM + h0 + rj) * HDIM;          // gates i,f
    const float* w1 = Whh + ((size_t)(rq + 2) * HDIM + h0 + rj) * HDIM;    // gates g,o
    fp16x8 b0[16], b1[16];
#pragma unroll
    for (int s = 0; s < 16; ++s) {
        const int k = kbase + s * 32 + kl;
        float4 a0 = *(const float4*)(w0 + k), a1 = *(const float4*)(w0 + k + 4);
        float4 c0 = *(const float4*)(w1 + k), c1 = *(const float4*)(w1 + k + 4);
        fp16x8 v;
        v[0] = (_Float16)a0.x; v[1] = (_Float16)a0.y; v[2] = (_Float16)a0.z; v[3] = (_Float16)a0.w;
        v[4] = (_Float16)a1.x; v[5] = (_Float16)a1.y; v[6] = (_Float16)a1.z; v[7] = (_Float16)a1.w;
        b0[s] = v;
        v[0] = (_Float16)c0.x; v[1] = (_Float16)c0.y; v[2] = (_Float16)c0.z; v[3] = (_Float16)c0.w;
        v[4] = (_Float16)c1.x; v[5] = (_Float16)c1.y; v[6] = (_Float16)c1.z; v[7] = (_Float16)c1.w;
        b1[s] = v;
    }
    float c_state = 0.f;
    const int uh = tid & 7, ub = tid >> 3;   // update thread: unit uh, batch ub

    // wave w consumes k-chunk from blocks [64w,64w+64): poll 1 producer/lane,
    // both flag arrays (wave0 = fa, wave1 = fb), replica blk&3.
    const int pidx = ((blk & 3) << 8) | (wave << 6) | lane;
    const int* fa = flags + (size_t)pidx * FLAG_STRIDE;
    const int* fb = fa + FB_OFF;

    __syncthreads();

    for (int t = 0; t < TSEQ; ++t) {
        if (t) {   // wait: both update-waves of my 64 producers published h_{t-1}
            while (__hip_atomic_load(fa, __ATOMIC_RELAXED, __HIP_MEMORY_SCOPE_AGENT) < flag_base + t ||
                   __hip_atomic_load(fb, __ATOMIC_RELAXED, __HIP_MEMORY_SCOPE_AGENT) < flag_base + t) {}
        }
        asm volatile("" ::: "memory");       // no load hoisting above poll
        const _Float16* hsrc = hstep + (size_t)t * HSTEP_ELEMS;

        // h_{t-1} fragments (issued FIRST: their counted vmcnt wait excludes xp)
        fp16x8 af[16];
#pragma unroll
        for (int s = 0; s < 16; ++s) {
            const int k = kbase + s * 32 + kl;
            af[s] = *(const fp16x8*)(hsrc + (size_t)k * 16 + ln15 * 8);
        }

        // xp[t] loads issued now; consumed after the barrier (drained there).
        float xi = 0.f, xf = 0.f, xg = 0.f, xo = 0.f;
        if (tid < 128) {
            const float* xpt = xp + ((size_t)t * BATCH + ub) * GATES + h0 + uh;
            xi = xpt[0];
            xf = xpt[HDIM];
            xg = xpt[2 * HDIM];
            xo = xpt[3 * HDIM];
        }

        // MFMA: 4 independent accumulator chains (even/odd k), merged after.
        f32x4 a0e = {0.f,0.f,0.f,0.f}, a0o = {0.f,0.f,0.f,0.f};
        f32x4 a1e = {0.f,0.f,0.f,0.f}, a1o = {0.f,0.f,0.f,0.f};
#pragma unroll
        for (int s = 0; s < 16; s += 2) {
            a0e = __builtin_amdgcn_mfma_f32_16x16x32_f16(af[s],     b0[s],     a0e, 0, 0, 0);
            a1e = __builtin_amdgcn_mfma_f32_16x16x32_f16(af[s],     b1[s],     a1e, 0, 0, 0);
            a0o = __builtin_amdgcn_mfma_f32_16x16x32_f16(af[s + 1], b0[s + 1], a0o, 0, 0, 0);
            a1o = __builtin_amdgcn_mfma_f32_16x16x32_f16(af[s + 1], b1[s + 1], a1o, 0, 0, 0);
        }
        f32x4 acc0 = a0e + a0o;
        f32x4 acc1 = a1e + a1o;
        {
            float* r0 = red[t & 1] + ((wave * 2 + 0) * 16 + ln15) * RED_ST + (lane >> 4) * 4;
            float* r1 = red[t & 1] + ((wave * 2 + 1) * 16 + ln15) * RED_ST + (lane >> 4) * 4;
#pragma unroll
            for (int i = 0; i < 4; ++i) { r0[i] = acc0[i]; r1[i] = acc1[i]; }
        }
        __syncthreads();                     // single per-step barrier (drains xp too)
        asm volatile("" ::: "memory");

        if (tid < 128) {
            const float* redp = red[t & 1];
            float ip = xi, fp_ = xf, gp = xg, op = xo;
#pragma unroll
            for (int w = 0; w < 4; ++w) {
                ip  += redp[((w * 2 + 0) * 16 + uh    ) * RED_ST + ub];
                fp_ += redp[((w * 2 + 0) * 16 + uh + 8) * RED_ST + ub];
                gp  += redp[((w * 2 + 1) * 16 + uh    ) * RED_ST + ub];
                op  += redp[((w * 2 + 1) * 16 + uh + 8) * RED_ST + ub];
            }
            float ig = sigmoidf_(ip), fg = sigmoidf_(fp_), og = sigmoidf_(op);
            float gg = tanhf_(gp);
            c_state = fg * c_state + ig * gg;
            float hv = og * tanhf_(c_state);
            HU cv; cv.f = (_Float16)hv;
            unsigned v  = cv.u;
            unsigned v1 = __shfl_down(v, 1, 64);
            unsigned v2 = __shfl_down(v, 2, 64);
            unsigned v3 = __shfl_down(v, 3, 64);
            if ((tid & 3) == 0) {            // pack 4 units -> 8B write-through store
                unsigned long long pk = (unsigned long long)v
                                      | ((unsigned long long)v1 << 16)
                                      | ((unsigned long long)v2 << 32)
                                      | ((unsigned long long)v3 << 48);
                unsigned long long* dst = (unsigned long long*)
                    (hstep + (size_t)(t + 1) * HSTEP_ELEMS + blk * HSLOT + ub * 8 + uh);
                __hip_atomic_store(dst, pk, __ATOMIC_RELAXED, __HIP_MEMORY_SCOPE_AGENT);
            }
            if (t < TSEQ - 1) {
                asm volatile("s_waitcnt vmcnt(0)" ::: "memory");   // own h stores at L3
                if (lane == 0) {             // wave0 -> fa[blk], wave1 -> fb[blk]
                    int* base = flags + (wave ? FB_OFF : 0);
#pragma unroll
                    for (int c = 0; c < NFLAG_COPY; ++c)
                        __hip_atomic_store(base + (size_t)((c << 8) | blk) * FLAG_STRIDE,
                                           flag_base + t + 1,
                                           __ATOMIC_RELAXED, __HIP_MEMORY_SCOPE_AGENT);
                }
            }
        }
    }
}

// ---------------- output projection -----------------------------------------
__global__ __launch_bounds__(256) void outproj_kernel(
        const _Float16* __restrict__ hstep, const float* __restrict__ Wout,
        const float* __restrict__ bout, float* __restrict__ out) {
    const int lane = threadIdx.x & 63;
    const int wave = threadIdx.x >> 6;
    const int tok = blockIdx.x * 4 + wave;
    const int b = tok >> 7, t = tok & 127;
    const _Float16* h = hstep + (size_t)(t + 1) * HSTEP_ELEMS + b * 8;
    float acc = 0.f;
#pragma unroll
    for (int c = 0; c < 4; ++c) {
        const int k = c * 512 + lane * 8;
        fp16x8 hv = *(const fp16x8*)(h + (size_t)k * 16);
        const float* w = Wout + k;
#pragma unroll
        for (int i = 0; i < 8; ++i) acc += (float)hv[i] * w[i];
    }
#pragma unroll
    for (int off = 32; off > 0; off >>= 1) acc += __shfl_down(acc, off, 64);
    if (lane == 0) out[tok] = acc + bout[0];
}

// ---------------- launch -----------------------------------------------------
extern "C" void kernel_launch(void* const* d_in, const int* in_sizes, int n_in,
                              void* d_out, int out_size, void* d_ws, size_t ws_size,
                              hipStream_t stream) {
    (void)in_sizes; (void)n_in; (void)out_size; (void)ws_size;
    const float* x       = (const float*)d_in[0];
    const float* Wih[3]  = {(const float*)d_in[1], (const float*)d_in[5], (const float*)d_in[9]};
    const float* Whh[3]  = {(const float*)d_in[2], (const float*)d_in[6], (const float*)d_in[10]};
    const float* bih[3]  = {(const float*)d_in[3], (const float*)d_in[7], (const float*)d_in[11]};
    const float* bhh[3]  = {(const float*)d_in[4], (const float*)d_in[8], (const float*)d_in[12]};
    const float* Wout    = (const float*)d_in[13];
    const float* bout    = (const float*)d_in[14];
    float* out = (float*)d_out;

    char* ws = (char*)d_ws;
    size_t off = 0;
    auto carve = [&](size_t bytes) {
        char* p = ws + off;
        off += (bytes + 255) & ~(size_t)255;
        return p;
    };
    _Float16* wih16 = (_Float16*)carve((size_t)GATES * 2048 * 2);             // 33.5 MB
    float*    xp    = (float*)   carve((size_t)TSEQ * GATES * BATCH * 4);     // 67 MB
    _Float16* xh    = (_Float16*)carve((size_t)NTOK * 128 * 2);               // 0.5 MB
    _Float16* hstep = (_Float16*)carve((size_t)(TSEQ + 1) * HSTEP_ELEMS * 2); // 8.46 MB
    int*      flags = (int*)     carve((size_t)2 * NFLAG_COPY * 256 * FLAG_STRIDE * 4); // 128 KB

    // one-time init (captured in graph, re-runs each replay)
    hipMemsetAsync(flags, 0, (size_t)2 * NFLAG_COPY * 256 * FLAG_STRIDE * 4, stream);
    hipMemsetAsync(hstep, 0, HSTEP_ELEMS * 2, stream);   // slot 0 = h_{-1} = 0

    {   // x -> fp16
        int n8 = NTOK * 128 / 8;
        cvt_f32_f16_kernel<<<(n8 + 255) / 256, 256, 0, stream>>>(x, xh, n8);
    }

    const int Kl[3] = {128, 2048, 2048};
    for (int l = 0; l < 3; ++l) {
        int n8 = GATES * Kl[l] / 8;
        cvt_f32_f16_kernel<<<(n8 + 255) / 256, 256, 0, stream>>>(Wih[l], wih16, n8);
        dim3 ggrid(GATES / 128, NTOK / 128);
        xproj_gemm_kernel<<<ggrid, 256, 0, stream>>>(
            l == 0 ? xh : nullptr, l == 0 ? nullptr : hstep,
            wih16, bih[l], bhh[l], xp, Kl[l]);
        lstm_scan_kernel<<<256, 256, 0, stream>>>(Whh[l], xp, hstep, flags, l * TSEQ);
    }
    outproj_kernel<<<NTOK / 4, 256, 0, stream>>>(hstep, Wout, bout, out);
}